// Round 9
// baseline (259.232 us; speedup 1.0000x reference)
//
#include <hip/hip_runtime.h>
#include <stdint.h>

// SpatialSelfAttention: B=4, C=512, P=4096, 32 groups.
// Pipeline (round 16: revert counted-vmcnt (neutral, r8); EXP -> TM=64):
//   Round-8 postmortem: T4 counted-vmcnt on PV was NEUTRAL (4-wave
//   lockstep 2-phase has no role-split for it to exploit); EXP's +7us was
//   co-compile/codegen perturbation (bytes identical). Revert PV to the
//   r6/r7 __syncthreads ping-pong dbuf (-10us measured).
//   Forward: EXP is block-TLP-bound (confirmed r2/r4/r6). Shrink EXP tile
//   128x128 -> 64x128 (grid 8192, LDS 24KB, VGPR ~64): ~6 blocks/CU vs 2,
//   occupancy 27% -> ~70%. Staging pattern == verified gemm_tn<EPI_V,64>.
//   1. cvt weights fp32->bf16 (wq,bq prescaled by 1.02014 = qscale2/2^-4)
//   2. gn_stats + gn_norm -> h_t [B*P, C] bf16 (LDS tile transpose)
//   3. qk8 = h_t @ [wq;wk]^T  [B*P, 1024] fp8 e4m3
//      v_c = wv @ h_t^T       [C, B*P]  fp8 e4m3
//   4. P[b] = exp2(2^-4 * q8[b] @ k8[b]^T)  [P,P] fp8 via MX-scaled
//      mfma_scale_f32_16x16x128_f8f6f4 (A-scale e8m0=123 -> 2^-4).
//      64x128 tile, single-buffer, 24KB LDS (TLP regime).
//   5. h_at[b] = (P[b] @ v_c[b]^T) / (P[b] @ 1)  [P, C] bf16 (ones-MFMA
//      rowsum). 128x128, 2-phase __syncthreads dbuf.
//   6. out = wo @ h_at^T + bo + x  [C, B*P] fp32 == d_out layout
// QK/EXP/PV use bijective XCD swizzle; V/OUT keep default (already local).

typedef __bf16 bf16_t;
typedef __attribute__((ext_vector_type(4))) __bf16 bf16x4;
typedef __attribute__((ext_vector_type(8))) __bf16 bf16x8;
typedef __attribute__((ext_vector_type(4))) float floatx4;
typedef __attribute__((ext_vector_type(8))) int intx8;

constexpr int CDIM = 512;
constexpr int PDIM = 4096;

constexpr int ctz_c(int n) { return (n & 1) ? 0 : 1 + ctz_c(n >> 1); }

__device__ __forceinline__ void ld_g2l(const void* g, void* l) {
  __builtin_amdgcn_global_load_lds(
      (const __attribute__((address_space(1))) void*)g,
      (__attribute__((address_space(3))) void*)l,
      16, 0, 0);
}

__device__ __forceinline__ uint32_t pk_fp8x4(float a, float b, float c,
                                             float d) {
  int r = __builtin_amdgcn_cvt_pk_fp8_f32(a, b, 0, false);
  r = __builtin_amdgcn_cvt_pk_fp8_f32(c, d, r, true);
  return (uint32_t)r;
}

// two 16B LDS chunks -> one 8-reg MFMA fragment (SROA keeps it in regs)
__device__ __forceinline__ intx8 ld_frag(const uint8_t* base, int s0,
                                         int s1) {
  union {
    uint4 u[2];
    intx8 v;
  } r;
  r.u[0] = *(const uint4*)(base + s0);
  r.u[1] = *(const uint4*)(base + s1);
  return r.v;
}

// bijective row permutation for B staging: LDS row 16ni+fr holds global
// col 4fr+ni -> each lane's 4 ni-values are 4 consecutive columns.
__device__ __forceinline__ int sigma_row(int r) {
  return (r & 64) + ((r & 15) << 2) + ((r >> 4) & 3);
}

// bijective XCD-aware remap, compile-time pow2 grid -> pure shift/mask.
template <int GX, int GY, int GZ>
__device__ __forceinline__ void xcd_remap(int& bx, int& by, int& bz) {
  constexpr int NWG = GX * GY * GZ;
  static_assert((NWG & 7) == 0 && (GX & (GX - 1)) == 0 &&
                    (GY & (GY - 1)) == 0,
                "pow2 grid, nwg%8==0");
  int lin = bx + GX * (by + GY * bz);
  int wg = (lin & 7) * (NWG >> 3) + (lin >> 3);
  bx = wg & (GX - 1);
  int t = wg >> ctz_c(GX);
  by = t & (GY - 1);
  bz = t >> ctz_c(GY);
}

enum { EPI_QK = 0, EPI_V = 1, EPI_OUT = 4, EPI_EXP = 2, EPI_PV = 5 };

// TN GEMM (bf16): C[M,N] = A[M,K] * B[N,K]^T, TMx128 tile, BK=64, NT thr,
// 16x16x32 MFMA, sigma-staged B + packed epilogue stores. K/strides are
// compile-time; K-loop fully unrolled (8 iters).
template <int EPI, int TM, int NT, bool SWZ, int K, int LDA, int LDB,
          int LDC, int GX = 1, int GY = 1, int GZ = 1>
__global__ __launch_bounds__(NT) void gemm_tn(
    const bf16_t* __restrict__ A, const bf16_t* __restrict__ B, long sAb,
    long sBb, long sCb, void* __restrict__ Cv,
    const float* __restrict__ bias, const float* __restrict__ xres) {
  constexpr int NW = NT / 64;
  constexpr int WROWS = TM / (NW / 2);
  constexpr int MI = WROWS / 16;
  constexpr int RB = NT / 8;    // rows staged per batch
  constexpr int AB = TM / RB;   // A stage batches
  constexpr int BB = 128 / RB;  // B stage batches
  constexpr int PMAX = AB > BB ? AB : BB;
  __shared__ bf16_t Asm[TM * 64];
  __shared__ bf16_t Bsm[128 * 64];

  const int tid = threadIdx.x;
  const int w = tid >> 6, l = tid & 63;
  int bx = blockIdx.x, by = blockIdx.y, bz = blockIdx.z;
  if constexpr (SWZ) xcd_remap<GX, GY, GZ>(bx, by, bz);
  const int m0 = by * TM, n0 = bx * 128;

  const bf16_t* Ab = A + (long)bz * sAb + (long)m0 * LDA;
  const bf16_t* Bb = B + (long)bz * sBb + (long)n0 * LDB;

  const int r0 = 8 * w + (l >> 3);
  const int schunk = (l & 7) ^ (l >> 3);
  const bf16_t* ga = Ab + (long)r0 * LDA + schunk * 8;
  const bf16_t* gb = Bb + schunk * 8;
  bf16_t* lA = Asm + (8 * w) * 64;
  bf16_t* lB = Bsm + (8 * w) * 64;

  const int wr = w >> 1, wc = w & 1;
  const int fr = l & 15, fq = l >> 4, l7 = l & 7;

  floatx4 acc[MI][4];
  floatx4 zz = {0.f, 0.f, 0.f, 0.f};
#pragma unroll
  for (int i = 0; i < MI; i++)
#pragma unroll
    for (int j = 0; j < 4; j++) acc[i][j] = zz;

#pragma unroll 8
  for (int it = 0; it < K / 64; it++) {
    const int kb = it * 64;
#pragma unroll
    for (int p = 0; p < PMAX; p++) {
      if (p < AB) ld_g2l(ga + (long)(p * RB) * LDA + kb, lA + p * RB * 64);
      if (p < BB) {
        const int sig = sigma_row(r0 + RB * p);  // B rows sigma-permuted
        ld_g2l(gb + (long)sig * LDB + kb, lB + p * RB * 64);
      }
    }
    __syncthreads();
#pragma unroll
    for (int ks = 0; ks < 2; ks++) {
      bf16x8 af[MI], bfv[4];
      const int ch = (ks * 4 + fq);
#pragma unroll
      for (int mi = 0; mi < MI; mi++) {
        int row = wr * WROWS + mi * 16 + fr;
        af[mi] = *(const bf16x8*)(Asm + row * 64 + ((ch ^ l7) * 8));
      }
#pragma unroll
      for (int ni = 0; ni < 4; ni++) {
        int row = wc * 64 + ni * 16 + fr;  // row&7 == l7
        bfv[ni] = *(const bf16x8*)(Bsm + row * 64 + ((ch ^ l7) * 8));
      }
#pragma unroll
      for (int mi = 0; mi < MI; mi++)
#pragma unroll
        for (int ni = 0; ni < 4; ni++)
          acc[mi][ni] = __builtin_amdgcn_mfma_f32_16x16x32_bf16(
              af[mi], bfv[ni], acc[mi][ni], 0, 0, 0);
    }
    __syncthreads();
  }

  // epilogue: sigma staging => MFMA ni, lane fr holds global col 4fr+ni
  const int rb = fq * 4;
  const int gcolb = n0 + wc * 64 + 4 * fr;
#pragma unroll
  for (int mi = 0; mi < MI; mi++) {
#pragma unroll
    for (int i = 0; i < 4; i++) {
      const int grow = m0 + wr * WROWS + mi * 16 + rb + i;
      float v0 = acc[mi][0][i], v1 = acc[mi][1][i];
      float v2 = acc[mi][2][i], v3 = acc[mi][3][i];
      if constexpr (EPI == EPI_QK) {
        // fp8 q||k output (q side pre-scaled via weights)
        const float4 b4 = *(const float4*)(bias + gcolb);
        *(uint32_t*)((uint8_t*)Cv + (long)bz * sCb + (long)grow * LDC +
                     gcolb) =
            pk_fp8x4(v0 + b4.x, v1 + b4.y, v2 + b4.z, v3 + b4.w);
      } else if constexpr (EPI == EPI_V) {
        const float bb = bias[grow];
        uint32_t d = pk_fp8x4(v0 + bb, v1 + bb, v2 + bb, v3 + bb);
        *(uint32_t*)((uint8_t*)Cv + (long)bz * sCb + (long)grow * LDC +
                     gcolb) = d;
      } else {  // EPI_OUT: grow = out channel, gcolb = b*P+p (4-aligned)
        int ob = gcolb >> 12, op = gcolb & 4095;
        long o = ((long)ob * CDIM + grow) * PDIM + op;
        const float4 xr = *(const float4*)(xres + o);
        const float bb = bias[grow];
        float4 ov = {v0 + bb + xr.x, v1 + bb + xr.y, v2 + bb + xr.z,
                     v3 + bb + xr.w};
        *(float4*)((float*)Cv + o) = ov;
      }
    }
  }
}

// fp8 TN GEMM via MX-scaled MFMA: C[M,N] op( A[M,K] * B[N,K]^T * 2^(SA-127) )
// TMx128 tile, BK=128, NT thr, mfma_scale_f32_16x16x128_f8f6f4.
// EPI_EXP: C = fp8(exp2(acc)). EPI_PV: C = bf16(acc / (P@1)) via ones-MFMA.
// DBUF=false: single-buffer 2-barrier loop (TLP regime, short K).
// DBUF=true : 2-phase __syncthreads ping-pong (stage next before compute,
//             one barrier per tile; static buf indices via unroll-by-2).
template <int EPI, int TM, int SA, int NT, int K, int LDA, int LDB, int LDC,
          int GX, int GY, int GZ, bool DBUF>
__global__ __launch_bounds__(NT) void gemm_f8(
    const uint8_t* __restrict__ A, const uint8_t* __restrict__ B, long sAb,
    long sBb, long sCb, void* __restrict__ Cv) {
  constexpr int NW = NT / 64;
  constexpr int WROWS = TM / (NW / 2);
  constexpr int MI = WROWS / 16;
  constexpr int RB = NT / 8;
  constexpr int AB = TM / RB;
  constexpr int BB = 128 / RB;
  constexpr int PMAX = AB > BB ? AB : BB;
  constexpr int NITER = K / 128;
  constexpr int NBUF = DBUF ? 2 : 1;
  static_assert(!DBUF || (NITER & 1) == 0, "ping-pong needs even iters");
  __shared__ uint8_t Asm[NBUF][TM * 128];
  __shared__ uint8_t Bsm[NBUF][128 * 128];

  const int tid = threadIdx.x;
  const int w = tid >> 6, l = tid & 63;
  int bx = blockIdx.x, by = blockIdx.y, bz = blockIdx.z;
  xcd_remap<GX, GY, GZ>(bx, by, bz);
  const int m0 = by * TM, n0 = bx * 128;

  const uint8_t* Ab = A + (long)bz * sAb + (long)m0 * LDA;
  const uint8_t* Bb = B + (long)bz * sBb + (long)n0 * LDB;

  const int r0 = 8 * w + (l >> 3);
  const int schunk = (l & 7) ^ (l >> 3);
  const uint8_t* ga = Ab + (long)r0 * LDA + schunk * 16;
  const uint8_t* gb = Bb + schunk * 16;
  const int lofs = (8 * w) * 128;

  const int wr = w >> 1, wc = w & 1;
  const int fr = l & 15, fq = l >> 4, l7 = l & 7;

  floatx4 acc[MI][4];
  floatx4 accr[MI];  // PV row sums (P @ ones)
#pragma unroll
  for (int i = 0; i < MI; i++) {
#pragma unroll
    for (int j = 0; j < 4; j++) acc[i][j] = floatx4{0.f, 0.f, 0.f, 0.f};
    accr[i] = floatx4{0.f, 0.f, 0.f, 0.f};
  }

  const int s0 = ((2 * fq) ^ l7) * 16;
  const int s1 = ((2 * fq + 1) ^ l7) * 16;

  // issue the global_load_lds for K-tile kb into buffer buf
  auto stage = [&](int buf, int kb) {
#pragma unroll
    for (int p = 0; p < PMAX; p++) {
      if (p < AB)
        ld_g2l(ga + (long)(p * RB) * LDA + kb, &Asm[buf][lofs + p * RB * 128]);
      if (p < BB) {
        const int sig = sigma_row(r0 + RB * p);  // B rows sigma-permuted
        ld_g2l(gb + (long)sig * LDB + kb, &Bsm[buf][lofs + p * RB * 128]);
      }
    }
  };
  // ds_read fragments from buffer buf and run the MFMA cluster
  auto compute = [&](int buf) {
    intx8 af[MI];
#pragma unroll
    for (int mi = 0; mi < MI; mi++)
      af[mi] =
          ld_frag(&Asm[buf][(wr * WROWS + mi * 16 + fr) * 128], s0, s1);
#pragma unroll
    for (int ni = 0; ni < 4; ni++) {
      // row&7 == l7 -> conflict-free
      intx8 bf = ld_frag(&Bsm[buf][(wc * 64 + ni * 16 + fr) * 128], s0, s1);
#pragma unroll
      for (int mi = 0; mi < MI; mi++)
        acc[mi][ni] = __builtin_amdgcn_mfma_scale_f32_16x16x128_f8f6f4(
            af[mi], bf, acc[mi][ni], 0, 0, 0, SA, 0, 127);
    }
    if constexpr (EPI == EPI_PV) {
      const int one8 = 0x38383838;  // 4x fp8 e4m3 1.0
      const intx8 ones = {one8, one8, one8, one8, one8, one8, one8, one8};
#pragma unroll
      for (int mi = 0; mi < MI; mi++)
        accr[mi] = __builtin_amdgcn_mfma_scale_f32_16x16x128_f8f6f4(
            af[mi], ones, accr[mi], 0, 0, 0, SA, 0, 127);
    }
  };

  if constexpr (DBUF) {
    stage(0, 0);
    __syncthreads();  // vmcnt(0) drain of prologue stage
#pragma unroll 1
    for (int it = 0; it < NITER; it += 2) {
      stage(1, (it + 1) * 128);  // issue next tile, compute under it
      compute(0);
      __syncthreads();
      if (it + 2 < NITER) stage(0, (it + 2) * 128);
      compute(1);
      __syncthreads();
    }
  } else {
#pragma unroll 1
    for (int it = 0; it < NITER; it++) {
      stage(0, it * 128);
      __syncthreads();
      compute(0);
      __syncthreads();
    }
  }

  const int rb = fq * 4;
  const int gcolb = n0 + wc * 64 + 4 * fr;
#pragma unroll
  for (int mi = 0; mi < MI; mi++) {
#pragma unroll
    for (int i = 0; i < 4; i++) {
      const int grow = m0 + wr * WROWS + mi * 16 + rb + i;
      if constexpr (EPI == EPI_EXP) {
        // acc already in log2 units (weight prescale + 2^-4 MX scale)
        float p0 = exp2f(acc[mi][0][i]), p1 = exp2f(acc[mi][1][i]);
        float p2 = exp2f(acc[mi][2][i]), p3 = exp2f(acc[mi][3][i]);
        *(uint32_t*)((uint8_t*)Cv + (long)bz * sCb + (long)grow * LDC +
                     gcolb) = pk_fp8x4(p0, p1, p2, p3);
      } else {  // EPI_PV: every column of accr == rowsum for this row
        const float inv = __builtin_amdgcn_rcpf(accr[mi][i]);
        bf16x4 o = {(bf16_t)(acc[mi][0][i] * inv),
                    (bf16_t)(acc[mi][1][i] * inv),
                    (bf16_t)(acc[mi][2][i] * inv),
                    (bf16_t)(acc[mi][3][i] * inv)};
        *(bf16x4*)((bf16_t*)Cv + (long)bz * sCb + (long)grow * LDC + gcolb) =
            o;
      }
    }
  }
}

// Stage 1: partial sums. Block i reads x[i*8192 .. +8192), writes (sum, sumsq).
__global__ __launch_bounds__(256) void gn_stats(const float* __restrict__ x,
                                                float2* __restrict__ part) {
  const int i = blockIdx.x;
  const float4* xp = (const float4*)(x + (long)i * 8192);
  float s0 = 0.f, s1 = 0.f;
  for (int j = threadIdx.x; j < 2048; j += 256) {
    float4 v = xp[j];
    s0 += v.x + v.y + v.z + v.w;
    s1 += v.x * v.x + v.y * v.y + v.z * v.z + v.w * v.w;
  }
  for (int o = 32; o; o >>= 1) {
    s0 += __shfl_xor(s0, o);
    s1 += __shfl_xor(s1, o);
  }
  __shared__ float r0[4], r1[4];
  if ((threadIdx.x & 63) == 0) {
    r0[threadIdx.x >> 6] = s0;
    r1[threadIdx.x >> 6] = s1;
  }
  __syncthreads();
  if (threadIdx.x == 0)
    part[i] = make_float2(r0[0] + r0[1] + r0[2] + r0[3],
                          r1[0] + r1[1] + r1[2] + r1[3]);
}

// Stage 2: normalize + transpose via LDS tile. Block = (b, 32 p-rows).
__global__ __launch_bounds__(256) void gn_norm(
    const float* __restrict__ x, const float* __restrict__ gamma,
    const float* __restrict__ beta, const float2* __restrict__ part,
    bf16_t* __restrict__ h_t) {
  const int b = blockIdx.x >> 7;
  const int p0 = (blockIdx.x & 127) * 32;
  const int t = threadIdx.x;
  __shared__ float gmS[512], btS[512];
  __shared__ float gmean[32], grstd[32];
  __shared__ __align__(16) bf16_t tile[32 * 520];

  if (t < 32) {
    const float2* pp = part + (b * 32 + t) * 8;
    float s0 = 0.f, s1 = 0.f;
#pragma unroll
    for (int s = 0; s < 8; s++) {
      float2 v = pp[s];
      s0 += v.x;
      s1 += v.y;
    }
    float mean = s0 * (1.f / 65536.f);
    float var = s1 * (1.f / 65536.f) - mean * mean;
    gmean[t] = mean;
    grstd[t] = rsqrtf(var + 1e-6f);
  }
  __syncthreads();
  for (int c = t; c < 512; c += 256) {
    float g = gamma[c] * grstd[c >> 4];
    gmS[c] = g;
    btS[c] = beta[c] - gmean[c >> 4] * g;
  }
  __syncthreads();

  const int cc = t >> 3, pcol = (t & 7) * 4;
  for (int pass = 0; pass < 16; pass++) {
    int c = pass * 32 + cc;
    float4 v = *(const float4*)(x + ((long)(b * 512 + c)) * 4096 + p0 + pcol);
    float g = gmS[c], bb = btS[c];
    tile[(pcol + 0) * 520 + c] = (bf16_t)(v.x * g + bb);
    tile[(pcol + 1) * 520 + c] = (bf16_t)(v.y * g + bb);
    tile[(pcol + 2) * 520 + c] = (bf16_t)(v.z * g + bb);
    tile[(pcol + 3) * 520 + c] = (bf16_t)(v.w * g + bb);
  }
  __syncthreads();
  const int p = t >> 3;
  bf16_t* orow = h_t + ((long)(b * 4096 + p0 + p)) * 512;
  const bf16_t* trow = tile + p * 520;
#pragma unroll
  for (int j = 0; j < 8; j++) {
    int ch = (t & 7) + 8 * j;
    *(uint4*)(orow + ch * 8) = *(const uint4*)(trow + ch * 8);
  }
}

// wq,bq prescaled by (log2e/sqrt(512)) / 2^-4 so the EXP GEMM's e8m0
// A-scale of 123 (2^-4) yields log2-domain scores directly.
__global__ __launch_bounds__(256) void cvt_weights(
    const float* __restrict__ wq, const float* __restrict__ wk,
    const float* __restrict__ wv, const float* __restrict__ wo,
    const float* __restrict__ bq, const float* __restrict__ bk,
    bf16_t* __restrict__ out, float* __restrict__ bqk) {
  constexpr float QW = 1.02013936f;  // (1/sqrt(512))*log2(e) / 2^-4
  int i = blockIdx.x * 256 + threadIdx.x;
  out[i] = (bf16_t)(wq[i] * QW);
  out[262144 + i] = (bf16_t)wk[i];
  out[2 * 262144 + i] = (bf16_t)wv[i];
  out[3 * 262144 + i] = (bf16_t)wo[i];
  if (i < 512)
    bqk[i] = bq[i] * QW;
  else if (i < 1024)
    bqk[i] = bk[i - 512];
}

extern "C" void kernel_launch(void* const* d_in, const int* in_sizes, int n_in,
                              void* d_out, int out_size, void* d_ws,
                              size_t ws_size, hipStream_t stream) {
  const float* x = (const float*)d_in[0];
  const float* gamma = (const float*)d_in[1];
  const float* beta = (const float*)d_in[2];
  const float* wq = (const float*)d_in[3];
  const float* bq = (const float*)d_in[4];
  const float* wk = (const float*)d_in[5];
  const float* bk = (const float*)d_in[6];
  const float* wv = (const float*)d_in[7];
  const float* bv = (const float*)d_in[8];
  const float* wo = (const float*)d_in[9];
  const float* bo = (const float*)d_in[10];

  char* ws = (char*)d_ws;
  bf16_t* h_t = (bf16_t*)(ws);                  // [16384,512] bf16  @0
  uint8_t* qk8 = (uint8_t*)(ws + (16l << 20));  // [16384,1024] fp8  @16MB
  uint8_t* v_c = (uint8_t*)(ws + (48l << 20));  // [512,16384] fp8   @48MB
  bf16_t* h_at = (bf16_t*)(ws + (64l << 20));   // [16384,512] bf16  @64MB
  bf16_t* w_b = (bf16_t*)(ws + (80l << 20));    // 4x[512,512] bf16  @80MB
  float2* part = (float2*)(ws + (83l << 20));   // [1024] partials   @83MB
  float* bqk = (float*)(ws + (83l << 20) + (64l << 10));  // [1024]
  uint8_t* Sbuf = (uint8_t*)(ws + (84l << 20)); // [4,4096,4096] fp8 @84MB

  const long sQK8 = (long)PDIM * 1024;  // bytes per batch of qk8
  const long sS = (long)PDIM * PDIM;    // 16777216

  cvt_weights<<<1024, 256, 0, stream>>>(wq, wk, wv, wo, bq, bk, w_b, bqk);
  gn_stats<<<1024, 256, 0, stream>>>(x, part);
  gn_norm<<<512, 256, 0, stream>>>(x, gamma, beta, part, h_t);
  // fused q|k projection -> fp8: B = [wq;wk] rows 0..1023, bias bqk
  gemm_tn<EPI_QK, 128, 256, true, 512, 512, 512, 1024, 8, 128, 1>
      <<<dim3(8, 128, 1), 256, 0, stream>>>(h_t, w_b, 0, 0, 0, qk8, bqk,
                                            nullptr);
  gemm_tn<EPI_V, 64, 256, false, 512, 512, 512, 16384>
      <<<dim3(128, 8, 1), 256, 0, stream>>>(w_b + 2 * 262144, h_t, 0, 0, 0,
                                            v_c, bv, nullptr);
  // P = exp2(2^-4 * q8 k8^T) fp8 (unnormalized; sums computed in PV)
  // 64x128 tile: 8192 blocks, 24KB LDS -> ~6 blocks/CU (TLP regime)
  gemm_f8<EPI_EXP, 64, 123, 256, 512, 1024, 1024, 4096, 32, 64, 4, false>
      <<<dim3(32, 64, 4), 256, 0, stream>>>(qk8, qk8 + 512, sQK8, sQK8, sS,
                                            Sbuf);
  // h_at = (P @ v^T) / (P @ 1)  — MX-fp8 K=128 MFMA, rsum via ones-MFMA
  gemm_f8<EPI_PV, 128, 127, 256, 4096, 4096, 16384, 512, 4, 32, 4, true>
      <<<dim3(4, 32, 4), 256, 0, stream>>>(Sbuf, v_c, sS, 4096,
                                           (long)PDIM * CDIM, h_at);
  gemm_tn<EPI_OUT, 64, 256, false, 512, 512, 512, 4096>
      <<<dim3(128, 8, 1), 256, 0, stream>>>(w_b + 3 * 262144, h_at, 0, 0, 0,
                                            d_out, bo, x);
}

// Round 10
// 245.441 us; speedup vs baseline: 1.0562x; 1.0562x over previous
//
#include <hip/hip_runtime.h>
#include <stdint.h>

// SpatialSelfAttention: B=4, C=512, P=4096, 32 groups.
// Pipeline (round 17: EXP locked at r7 optimum; PV -> 256x128, 512 thr):
//   Round-9 postmortem: EXP TM=64 rejected (5th failed EXP tweak: occupancy
//   +35% but ds:MFMA ratio worsened, +50% bank conflicts -> 55.6us). EXP's
//   single-buffer TM=128 (50.2us, r7) is its local optimum — frozen.
//   PV cycle accounting: LDS frag-read BW is the binding pipe (128KB/iter/CU
//   = 1500cyc vs MFMA 1376, stage 1170). 256x128 tile @512thr halves LDS
//   frag bytes PER OUTPUT (8 waves 4x2: same 128KB reads, 2x output) and
//   cuts staging/FLOP 25%. Occupancy neutral (96KB LDS -> 1 blk/CU x 8
//   waves = same 2 waves/SIMD). K=4096's 32 iters amortize fill (unlike
//   r2's 4-iter EXP regression). Numerics bitwise identical.
//   1. cvt weights fp32->bf16 (wq,bq prescaled by 1.02014 = qscale2/2^-4)
//   2. gn_stats + gn_norm -> h_t [B*P, C] bf16 (LDS tile transpose)
//   3. qk8 = h_t @ [wq;wk]^T  [B*P, 1024] fp8 e4m3
//      v_c = wv @ h_t^T       [C, B*P]  fp8 e4m3
//   4. P[b] = exp2(2^-4 * q8[b] @ k8[b]^T)  [P,P] fp8 via MX-scaled
//      mfma_scale_f32_16x16x128_f8f6f4 (A-scale e8m0=123 -> 2^-4).
//      128x128 tile, single-buffer, 32KB LDS (TLP regime).
//   5. h_at[b] = (P[b] @ v_c[b]^T) / (P[b] @ 1)  [P, C] bf16 (ones-MFMA
//      rowsum). 256x128 tile, 512 thr, 2-phase __syncthreads dbuf.
//   6. out = wo @ h_at^T + bo + x  [C, B*P] fp32 == d_out layout
// QK/EXP/PV use bijective XCD swizzle; V/OUT keep default (already local).

typedef __bf16 bf16_t;
typedef __attribute__((ext_vector_type(4))) __bf16 bf16x4;
typedef __attribute__((ext_vector_type(8))) __bf16 bf16x8;
typedef __attribute__((ext_vector_type(4))) float floatx4;
typedef __attribute__((ext_vector_type(8))) int intx8;

constexpr int CDIM = 512;
constexpr int PDIM = 4096;

constexpr int ctz_c(int n) { return (n & 1) ? 0 : 1 + ctz_c(n >> 1); }

__device__ __forceinline__ void ld_g2l(const void* g, void* l) {
  __builtin_amdgcn_global_load_lds(
      (const __attribute__((address_space(1))) void*)g,
      (__attribute__((address_space(3))) void*)l,
      16, 0, 0);
}

__device__ __forceinline__ uint32_t pk_fp8x4(float a, float b, float c,
                                             float d) {
  int r = __builtin_amdgcn_cvt_pk_fp8_f32(a, b, 0, false);
  r = __builtin_amdgcn_cvt_pk_fp8_f32(c, d, r, true);
  return (uint32_t)r;
}

// two 16B LDS chunks -> one 8-reg MFMA fragment (SROA keeps it in regs)
__device__ __forceinline__ intx8 ld_frag(const uint8_t* base, int s0,
                                         int s1) {
  union {
    uint4 u[2];
    intx8 v;
  } r;
  r.u[0] = *(const uint4*)(base + s0);
  r.u[1] = *(const uint4*)(base + s1);
  return r.v;
}

// bijective row permutation for B staging: LDS row 16ni+fr holds global
// col 4fr+ni -> each lane's 4 ni-values are 4 consecutive columns.
__device__ __forceinline__ int sigma_row(int r) {
  return (r & 64) + ((r & 15) << 2) + ((r >> 4) & 3);
}

// bijective XCD-aware remap, compile-time pow2 grid -> pure shift/mask.
template <int GX, int GY, int GZ>
__device__ __forceinline__ void xcd_remap(int& bx, int& by, int& bz) {
  constexpr int NWG = GX * GY * GZ;
  static_assert((NWG & 7) == 0 && (GX & (GX - 1)) == 0 &&
                    (GY & (GY - 1)) == 0,
                "pow2 grid, nwg%8==0");
  int lin = bx + GX * (by + GY * bz);
  int wg = (lin & 7) * (NWG >> 3) + (lin >> 3);
  bx = wg & (GX - 1);
  int t = wg >> ctz_c(GX);
  by = t & (GY - 1);
  bz = t >> ctz_c(GY);
}

enum { EPI_QK = 0, EPI_V = 1, EPI_OUT = 4, EPI_EXP = 2, EPI_PV = 5 };

// TN GEMM (bf16): C[M,N] = A[M,K] * B[N,K]^T, TMx128 tile, BK=64, NT thr,
// 16x16x32 MFMA, sigma-staged B + packed epilogue stores. K/strides are
// compile-time; K-loop fully unrolled (8 iters).
template <int EPI, int TM, int NT, bool SWZ, int K, int LDA, int LDB,
          int LDC, int GX = 1, int GY = 1, int GZ = 1>
__global__ __launch_bounds__(NT) void gemm_tn(
    const bf16_t* __restrict__ A, const bf16_t* __restrict__ B, long sAb,
    long sBb, long sCb, void* __restrict__ Cv,
    const float* __restrict__ bias, const float* __restrict__ xres) {
  constexpr int NW = NT / 64;
  constexpr int WROWS = TM / (NW / 2);
  constexpr int MI = WROWS / 16;
  constexpr int RB = NT / 8;    // rows staged per batch
  constexpr int AB = TM / RB;   // A stage batches
  constexpr int BB = 128 / RB;  // B stage batches
  constexpr int PMAX = AB > BB ? AB : BB;
  __shared__ bf16_t Asm[TM * 64];
  __shared__ bf16_t Bsm[128 * 64];

  const int tid = threadIdx.x;
  const int w = tid >> 6, l = tid & 63;
  int bx = blockIdx.x, by = blockIdx.y, bz = blockIdx.z;
  if constexpr (SWZ) xcd_remap<GX, GY, GZ>(bx, by, bz);
  const int m0 = by * TM, n0 = bx * 128;

  const bf16_t* Ab = A + (long)bz * sAb + (long)m0 * LDA;
  const bf16_t* Bb = B + (long)bz * sBb + (long)n0 * LDB;

  const int r0 = 8 * w + (l >> 3);
  const int schunk = (l & 7) ^ (l >> 3);
  const bf16_t* ga = Ab + (long)r0 * LDA + schunk * 8;
  const bf16_t* gb = Bb + schunk * 8;
  bf16_t* lA = Asm + (8 * w) * 64;
  bf16_t* lB = Bsm + (8 * w) * 64;

  const int wr = w >> 1, wc = w & 1;
  const int fr = l & 15, fq = l >> 4, l7 = l & 7;

  floatx4 acc[MI][4];
  floatx4 zz = {0.f, 0.f, 0.f, 0.f};
#pragma unroll
  for (int i = 0; i < MI; i++)
#pragma unroll
    for (int j = 0; j < 4; j++) acc[i][j] = zz;

#pragma unroll 8
  for (int it = 0; it < K / 64; it++) {
    const int kb = it * 64;
#pragma unroll
    for (int p = 0; p < PMAX; p++) {
      if (p < AB) ld_g2l(ga + (long)(p * RB) * LDA + kb, lA + p * RB * 64);
      if (p < BB) {
        const int sig = sigma_row(r0 + RB * p);  // B rows sigma-permuted
        ld_g2l(gb + (long)sig * LDB + kb, lB + p * RB * 64);
      }
    }
    __syncthreads();
#pragma unroll
    for (int ks = 0; ks < 2; ks++) {
      bf16x8 af[MI], bfv[4];
      const int ch = (ks * 4 + fq);
#pragma unroll
      for (int mi = 0; mi < MI; mi++) {
        int row = wr * WROWS + mi * 16 + fr;
        af[mi] = *(const bf16x8*)(Asm + row * 64 + ((ch ^ l7) * 8));
      }
#pragma unroll
      for (int ni = 0; ni < 4; ni++) {
        int row = wc * 64 + ni * 16 + fr;  // row&7 == l7
        bfv[ni] = *(const bf16x8*)(Bsm + row * 64 + ((ch ^ l7) * 8));
      }
#pragma unroll
      for (int mi = 0; mi < MI; mi++)
#pragma unroll
        for (int ni = 0; ni < 4; ni++)
          acc[mi][ni] = __builtin_amdgcn_mfma_f32_16x16x32_bf16(
              af[mi], bfv[ni], acc[mi][ni], 0, 0, 0);
    }
    __syncthreads();
  }

  // epilogue: sigma staging => MFMA ni, lane fr holds global col 4fr+ni
  const int rb = fq * 4;
  const int gcolb = n0 + wc * 64 + 4 * fr;
#pragma unroll
  for (int mi = 0; mi < MI; mi++) {
#pragma unroll
    for (int i = 0; i < 4; i++) {
      const int grow = m0 + wr * WROWS + mi * 16 + rb + i;
      float v0 = acc[mi][0][i], v1 = acc[mi][1][i];
      float v2 = acc[mi][2][i], v3 = acc[mi][3][i];
      if constexpr (EPI == EPI_QK) {
        // fp8 q||k output (q side pre-scaled via weights)
        const float4 b4 = *(const float4*)(bias + gcolb);
        *(uint32_t*)((uint8_t*)Cv + (long)bz * sCb + (long)grow * LDC +
                     gcolb) =
            pk_fp8x4(v0 + b4.x, v1 + b4.y, v2 + b4.z, v3 + b4.w);
      } else if constexpr (EPI == EPI_V) {
        const float bb = bias[grow];
        uint32_t d = pk_fp8x4(v0 + bb, v1 + bb, v2 + bb, v3 + bb);
        *(uint32_t*)((uint8_t*)Cv + (long)bz * sCb + (long)grow * LDC +
                     gcolb) = d;
      } else {  // EPI_OUT: grow = out channel, gcolb = b*P+p (4-aligned)
        int ob = gcolb >> 12, op = gcolb & 4095;
        long o = ((long)ob * CDIM + grow) * PDIM + op;
        const float4 xr = *(const float4*)(xres + o);
        const float bb = bias[grow];
        float4 ov = {v0 + bb + xr.x, v1 + bb + xr.y, v2 + bb + xr.z,
                     v3 + bb + xr.w};
        *(float4*)((float*)Cv + o) = ov;
      }
    }
  }
}

// fp8 TN GEMM via MX-scaled MFMA: C[M,N] op( A[M,K] * B[N,K]^T * 2^(SA-127) )
// TMx128 tile, BK=128, NT thr, mfma_scale_f32_16x16x128_f8f6f4.
// EPI_EXP: C = fp8(exp2(acc)). EPI_PV: C = bf16(acc / (P@1)) via ones-MFMA.
// DBUF=false: single-buffer 2-barrier loop (TLP regime, short K).
// DBUF=true : 2-phase __syncthreads ping-pong (stage next before compute,
//             one barrier per tile; static buf indices via unroll-by-2).
template <int EPI, int TM, int SA, int NT, int K, int LDA, int LDB, int LDC,
          int GX, int GY, int GZ, bool DBUF>
__global__ __launch_bounds__(NT) void gemm_f8(
    const uint8_t* __restrict__ A, const uint8_t* __restrict__ B, long sAb,
    long sBb, long sCb, void* __restrict__ Cv) {
  constexpr int NW = NT / 64;
  constexpr int WROWS = TM / (NW / 2);
  constexpr int MI = WROWS / 16;
  constexpr int RB = NT / 8;
  constexpr int AB = TM / RB;
  constexpr int BB = 128 / RB;
  constexpr int PMAX = AB > BB ? AB : BB;
  constexpr int NITER = K / 128;
  constexpr int NBUF = DBUF ? 2 : 1;
  static_assert(!DBUF || (NITER & 1) == 0, "ping-pong needs even iters");
  __shared__ uint8_t Asm[NBUF][TM * 128];
  __shared__ uint8_t Bsm[NBUF][128 * 128];

  const int tid = threadIdx.x;
  const int w = tid >> 6, l = tid & 63;
  int bx = blockIdx.x, by = blockIdx.y, bz = blockIdx.z;
  xcd_remap<GX, GY, GZ>(bx, by, bz);
  const int m0 = by * TM, n0 = bx * 128;

  const uint8_t* Ab = A + (long)bz * sAb + (long)m0 * LDA;
  const uint8_t* Bb = B + (long)bz * sBb + (long)n0 * LDB;

  const int r0 = 8 * w + (l >> 3);
  const int schunk = (l & 7) ^ (l >> 3);
  const uint8_t* ga = Ab + (long)r0 * LDA + schunk * 16;
  const uint8_t* gb = Bb + schunk * 16;
  const int lofs = (8 * w) * 128;

  const int wr = w >> 1, wc = w & 1;
  const int fr = l & 15, fq = l >> 4, l7 = l & 7;

  floatx4 acc[MI][4];
  floatx4 accr[MI];  // PV row sums (P @ ones)
#pragma unroll
  for (int i = 0; i < MI; i++) {
#pragma unroll
    for (int j = 0; j < 4; j++) acc[i][j] = floatx4{0.f, 0.f, 0.f, 0.f};
    accr[i] = floatx4{0.f, 0.f, 0.f, 0.f};
  }

  const int s0 = ((2 * fq) ^ l7) * 16;
  const int s1 = ((2 * fq + 1) ^ l7) * 16;

  // issue the global_load_lds for K-tile kb into buffer buf
  auto stage = [&](int buf, int kb) {
#pragma unroll
    for (int p = 0; p < PMAX; p++) {
      if (p < AB)
        ld_g2l(ga + (long)(p * RB) * LDA + kb, &Asm[buf][lofs + p * RB * 128]);
      if (p < BB) {
        const int sig = sigma_row(r0 + RB * p);  // B rows sigma-permuted
        ld_g2l(gb + (long)sig * LDB + kb, &Bsm[buf][lofs + p * RB * 128]);
      }
    }
  };
  // ds_read fragments from buffer buf and run the MFMA cluster
  auto compute = [&](int buf) {
    intx8 af[MI];
#pragma unroll
    for (int mi = 0; mi < MI; mi++)
      af[mi] =
          ld_frag(&Asm[buf][(wr * WROWS + mi * 16 + fr) * 128], s0, s1);
#pragma unroll
    for (int ni = 0; ni < 4; ni++) {
      // row&7 == l7 -> conflict-free
      intx8 bf = ld_frag(&Bsm[buf][(wc * 64 + ni * 16 + fr) * 128], s0, s1);
#pragma unroll
      for (int mi = 0; mi < MI; mi++)
        acc[mi][ni] = __builtin_amdgcn_mfma_scale_f32_16x16x128_f8f6f4(
            af[mi], bf, acc[mi][ni], 0, 0, 0, SA, 0, 127);
    }
    if constexpr (EPI == EPI_PV) {
      const int one8 = 0x38383838;  // 4x fp8 e4m3 1.0
      const intx8 ones = {one8, one8, one8, one8, one8, one8, one8, one8};
#pragma unroll
      for (int mi = 0; mi < MI; mi++)
        accr[mi] = __builtin_amdgcn_mfma_scale_f32_16x16x128_f8f6f4(
            af[mi], ones, accr[mi], 0, 0, 0, SA, 0, 127);
    }
  };

  if constexpr (DBUF) {
    stage(0, 0);
    __syncthreads();  // vmcnt(0) drain of prologue stage
#pragma unroll 1
    for (int it = 0; it < NITER; it += 2) {
      stage(1, (it + 1) * 128);  // issue next tile, compute under it
      compute(0);
      __syncthreads();
      if (it + 2 < NITER) stage(0, (it + 2) * 128);
      compute(1);
      __syncthreads();
    }
  } else {
#pragma unroll 1
    for (int it = 0; it < NITER; it++) {
      stage(0, it * 128);
      __syncthreads();
      compute(0);
      __syncthreads();
    }
  }

  const int rb = fq * 4;
  const int gcolb = n0 + wc * 64 + 4 * fr;
#pragma unroll
  for (int mi = 0; mi < MI; mi++) {
#pragma unroll
    for (int i = 0; i < 4; i++) {
      const int grow = m0 + wr * WROWS + mi * 16 + rb + i;
      if constexpr (EPI == EPI_EXP) {
        // acc already in log2 units (weight prescale + 2^-4 MX scale)
        float p0 = exp2f(acc[mi][0][i]), p1 = exp2f(acc[mi][1][i]);
        float p2 = exp2f(acc[mi][2][i]), p3 = exp2f(acc[mi][3][i]);
        *(uint32_t*)((uint8_t*)Cv + (long)bz * sCb + (long)grow * LDC +
                     gcolb) = pk_fp8x4(p0, p1, p2, p3);
      } else {  // EPI_PV: every column of accr == rowsum for this row
        const float inv = __builtin_amdgcn_rcpf(accr[mi][i]);
        bf16x4 o = {(bf16_t)(acc[mi][0][i] * inv),
                    (bf16_t)(acc[mi][1][i] * inv),
                    (bf16_t)(acc[mi][2][i] * inv),
                    (bf16_t)(acc[mi][3][i] * inv)};
        *(bf16x4*)((bf16_t*)Cv + (long)bz * sCb + (long)grow * LDC + gcolb) =
            o;
      }
    }
  }
}

// Stage 1: partial sums. Block i reads x[i*8192 .. +8192), writes (sum, sumsq).
__global__ __launch_bounds__(256) void gn_stats(const float* __restrict__ x,
                                                float2* __restrict__ part) {
  const int i = blockIdx.x;
  const float4* xp = (const float4*)(x + (long)i * 8192);
  float s0 = 0.f, s1 = 0.f;
  for (int j = threadIdx.x; j < 2048; j += 256) {
    float4 v = xp[j];
    s0 += v.x + v.y + v.z + v.w;
    s1 += v.x * v.x + v.y * v.y + v.z * v.z + v.w * v.w;
  }
  for (int o = 32; o; o >>= 1) {
    s0 += __shfl_xor(s0, o);
    s1 += __shfl_xor(s1, o);
  }
  __shared__ float r0[4], r1[4];
  if ((threadIdx.x & 63) == 0) {
    r0[threadIdx.x >> 6] = s0;
    r1[threadIdx.x >> 6] = s1;
  }
  __syncthreads();
  if (threadIdx.x == 0)
    part[i] = make_float2(r0[0] + r0[1] + r0[2] + r0[3],
                          r1[0] + r1[1] + r1[2] + r1[3]);
}

// Stage 2: normalize + transpose via LDS tile. Block = (b, 32 p-rows).
__global__ __launch_bounds__(256) void gn_norm(
    const float* __restrict__ x, const float* __restrict__ gamma,
    const float* __restrict__ beta, const float2* __restrict__ part,
    bf16_t* __restrict__ h_t) {
  const int b = blockIdx.x >> 7;
  const int p0 = (blockIdx.x & 127) * 32;
  const int t = threadIdx.x;
  __shared__ float gmS[512], btS[512];
  __shared__ float gmean[32], grstd[32];
  __shared__ __align__(16) bf16_t tile[32 * 520];

  if (t < 32) {
    const float2* pp = part + (b * 32 + t) * 8;
    float s0 = 0.f, s1 = 0.f;
#pragma unroll
    for (int s = 0; s < 8; s++) {
      float2 v = pp[s];
      s0 += v.x;
      s1 += v.y;
    }
    float mean = s0 * (1.f / 65536.f);
    float var = s1 * (1.f / 65536.f) - mean * mean;
    gmean[t] = mean;
    grstd[t] = rsqrtf(var + 1e-6f);
  }
  __syncthreads();
  for (int c = t; c < 512; c += 256) {
    float g = gamma[c] * grstd[c >> 4];
    gmS[c] = g;
    btS[c] = beta[c] - gmean[c >> 4] * g;
  }
  __syncthreads();

  const int cc = t >> 3, pcol = (t & 7) * 4;
  for (int pass = 0; pass < 16; pass++) {
    int c = pass * 32 + cc;
    float4 v = *(const float4*)(x + ((long)(b * 512 + c)) * 4096 + p0 + pcol);
    float g = gmS[c], bb = btS[c];
    tile[(pcol + 0) * 520 + c] = (bf16_t)(v.x * g + bb);
    tile[(pcol + 1) * 520 + c] = (bf16_t)(v.y * g + bb);
    tile[(pcol + 2) * 520 + c] = (bf16_t)(v.z * g + bb);
    tile[(pcol + 3) * 520 + c] = (bf16_t)(v.w * g + bb);
  }
  __syncthreads();
  const int p = t >> 3;
  bf16_t* orow = h_t + ((long)(b * 4096 + p0 + p)) * 512;
  const bf16_t* trow = tile + p * 520;
#pragma unroll
  for (int j = 0; j < 8; j++) {
    int ch = (t & 7) + 8 * j;
    *(uint4*)(orow + ch * 8) = *(const uint4*)(trow + ch * 8);
  }
}

// wq,bq prescaled by (log2e/sqrt(512)) / 2^-4 so the EXP GEMM's e8m0
// A-scale of 123 (2^-4) yields log2-domain scores directly.
__global__ __launch_bounds__(256) void cvt_weights(
    const float* __restrict__ wq, const float* __restrict__ wk,
    const float* __restrict__ wv, const float* __restrict__ wo,
    const float* __restrict__ bq, const float* __restrict__ bk,
    bf16_t* __restrict__ out, float* __restrict__ bqk) {
  constexpr float QW = 1.02013936f;  // (1/sqrt(512))*log2(e) / 2^-4
  int i = blockIdx.x * 256 + threadIdx.x;
  out[i] = (bf16_t)(wq[i] * QW);
  out[262144 + i] = (bf16_t)wk[i];
  out[2 * 262144 + i] = (bf16_t)wv[i];
  out[3 * 262144 + i] = (bf16_t)wo[i];
  if (i < 512)
    bqk[i] = bq[i] * QW;
  else if (i < 1024)
    bqk[i] = bk[i - 512];
}

extern "C" void kernel_launch(void* const* d_in, const int* in_sizes, int n_in,
                              void* d_out, int out_size, void* d_ws,
                              size_t ws_size, hipStream_t stream) {
  const float* x = (const float*)d_in[0];
  const float* gamma = (const float*)d_in[1];
  const float* beta = (const float*)d_in[2];
  const float* wq = (const float*)d_in[3];
  const float* bq = (const float*)d_in[4];
  const float* wk = (const float*)d_in[5];
  const float* bk = (const float*)d_in[6];
  const float* wv = (const float*)d_in[7];
  const float* bv = (const float*)d_in[8];
  const float* wo = (const float*)d_in[9];
  const float* bo = (const float*)d_in[10];

  char* ws = (char*)d_ws;
  bf16_t* h_t = (bf16_t*)(ws);                  // [16384,512] bf16  @0
  uint8_t* qk8 = (uint8_t*)(ws + (16l << 20));  // [16384,1024] fp8  @16MB
  uint8_t* v_c = (uint8_t*)(ws + (48l << 20));  // [512,16384] fp8   @48MB
  bf16_t* h_at = (bf16_t*)(ws + (64l << 20));   // [16384,512] bf16  @64MB
  bf16_t* w_b = (bf16_t*)(ws + (80l << 20));    // 4x[512,512] bf16  @80MB
  float2* part = (float2*)(ws + (83l << 20));   // [1024] partials   @83MB
  float* bqk = (float*)(ws + (83l << 20) + (64l << 10));  // [1024]
  uint8_t* Sbuf = (uint8_t*)(ws + (84l << 20)); // [4,4096,4096] fp8 @84MB

  const long sQK8 = (long)PDIM * 1024;  // bytes per batch of qk8
  const long sS = (long)PDIM * PDIM;    // 16777216

  cvt_weights<<<1024, 256, 0, stream>>>(wq, wk, wv, wo, bq, bk, w_b, bqk);
  gn_stats<<<1024, 256, 0, stream>>>(x, part);
  gn_norm<<<512, 256, 0, stream>>>(x, gamma, beta, part, h_t);
  // fused q|k projection -> fp8: B = [wq;wk] rows 0..1023, bias bqk
  gemm_tn<EPI_QK, 128, 256, true, 512, 512, 512, 1024, 8, 128, 1>
      <<<dim3(8, 128, 1), 256, 0, stream>>>(h_t, w_b, 0, 0, 0, qk8, bqk,
                                            nullptr);
  gemm_tn<EPI_V, 64, 256, false, 512, 512, 512, 16384>
      <<<dim3(128, 8, 1), 256, 0, stream>>>(w_b + 2 * 262144, h_t, 0, 0, 0,
                                            v_c, bv, nullptr);
  // P = exp2(2^-4 * q8 k8^T) fp8 (unnormalized; sums computed in PV)
  // r7-optimal shape: 128x128, single-buffer, 4096 blocks
  gemm_f8<EPI_EXP, 128, 123, 256, 512, 1024, 1024, 4096, 32, 32, 4, false>
      <<<dim3(32, 32, 4), 256, 0, stream>>>(qk8, qk8 + 512, sQK8, sQK8, sS,
                                            Sbuf);
  // h_at = (P @ v^T) / (P @ 1) — 256x128 tile, 512 thr (8 waves 4x2):
  // halves LDS frag bytes per output; 96KB LDS dbuf, 1 blk/CU x 8 waves
  gemm_f8<EPI_PV, 256, 127, 512, 4096, 4096, 16384, 512, 4, 16, 4, true>
      <<<dim3(4, 16, 4), 512, 0, stream>>>(Sbuf, v_c, sS, 4096,
                                           (long)PDIM * CDIM, h_at);
  gemm_tn<EPI_OUT, 64, 256, false, 512, 512, 512, 4096>
      <<<dim3(128, 8, 1), 256, 0, stream>>>(w_b + 3 * 262144, h_at, 0, 0, 0,
                                            d_out, bo, x);
}

// Round 11
// 237.357 us; speedup vs baseline: 1.0922x; 1.0341x over previous
//
#include <hip/hip_runtime.h>
#include <stdint.h>

// SpatialSelfAttention: B=4, C=512, P=4096, 32 groups.
// Pipeline (round 18: Q/K/V projections -> MX-fp8):
//   Round-10 postmortem: PV 256x128@512thr landed (245.4us best). Largest
//   remaining unconverted piece = bf16 projections (~40us combined). Move
//   QK and V projections to gemm_f8 (EXP's proven 128^2/4-iter shape, 2x
//   MFMA rate, half staging). Weights w~N(0,0.02) would be subnormal in
//   e4m3 -> prescale x2^6 in cvt_weights, compensate with e8m0 scale 121
//   (2^-6) on the weight operand. h is GN-normalized (sigma=1) -> fp8-safe;
//   gn_norm emits h8 fp8 directly (h_t bf16 now dead, store traffic halved).
//   r0->r1 evidence: q/k fp8-ization left absmax unchanged -> S-side noise
//   subdominant; v noise is softmax-averaged over ~4096 positions.
//   1. cvt weights: wq,wk,wv -> fp8 x64 (wq also x1.02014 = qscale2/2^-4);
//      wo -> bf16; bqk = [bq*1.02014 | bk]
//   2. gn_stats + gn_norm -> h8 [B*P, C] fp8 (LDS tile transpose)
//   3. qk8 = h8 @ [wq;wk]^T  [B*P, 1024] fp8  (MX GEMM, SA=127 SB=121)
//      v_c = wv @ h8^T       [C, B*P]  fp8    (MX GEMM, SA=121 SB=127)
//   4. P[b] = exp2(2^-4 * q8[b] @ k8[b]^T)  [P,P] fp8 MX (SA=123).
//      128x128 tile, single-buffer (TLP regime; locked since r7).
//   5. h_at[b] = (P[b] @ v_c[b]^T) / (P[b] @ 1)  [P, C] bf16 (ones-MFMA
//      rowsum). 256x128 tile, 512 thr, 2-phase __syncthreads dbuf.
//   6. out = wo @ h_at^T + bo + x  [C, B*P] fp32 == d_out (bf16 gemm_tn)
// All gemm_f8 use bijective XCD swizzle; OUT keeps default (already local).

typedef __bf16 bf16_t;
typedef __attribute__((ext_vector_type(4))) __bf16 bf16x4;
typedef __attribute__((ext_vector_type(8))) __bf16 bf16x8;
typedef __attribute__((ext_vector_type(4))) float floatx4;
typedef __attribute__((ext_vector_type(8))) int intx8;

constexpr int CDIM = 512;
constexpr int PDIM = 4096;

constexpr int ctz_c(int n) { return (n & 1) ? 0 : 1 + ctz_c(n >> 1); }

__device__ __forceinline__ void ld_g2l(const void* g, void* l) {
  __builtin_amdgcn_global_load_lds(
      (const __attribute__((address_space(1))) void*)g,
      (__attribute__((address_space(3))) void*)l,
      16, 0, 0);
}

__device__ __forceinline__ uint32_t pk_fp8x4(float a, float b, float c,
                                             float d) {
  int r = __builtin_amdgcn_cvt_pk_fp8_f32(a, b, 0, false);
  r = __builtin_amdgcn_cvt_pk_fp8_f32(c, d, r, true);
  return (uint32_t)r;
}

// two 16B LDS chunks -> one 8-reg MFMA fragment (SROA keeps it in regs)
__device__ __forceinline__ intx8 ld_frag(const uint8_t* base, int s0,
                                         int s1) {
  union {
    uint4 u[2];
    intx8 v;
  } r;
  r.u[0] = *(const uint4*)(base + s0);
  r.u[1] = *(const uint4*)(base + s1);
  return r.v;
}

// bijective row permutation for B staging: LDS row 16ni+fr holds global
// col 4fr+ni -> each lane's 4 ni-values are 4 consecutive columns.
__device__ __forceinline__ int sigma_row(int r) {
  return (r & 64) + ((r & 15) << 2) + ((r >> 4) & 3);
}

// bijective XCD-aware remap, compile-time pow2 grid -> pure shift/mask.
template <int GX, int GY, int GZ>
__device__ __forceinline__ void xcd_remap(int& bx, int& by, int& bz) {
  constexpr int NWG = GX * GY * GZ;
  static_assert((NWG & 7) == 0 && (GX & (GX - 1)) == 0 &&
                    (GY & (GY - 1)) == 0,
                "pow2 grid, nwg%8==0");
  int lin = bx + GX * (by + GY * bz);
  int wg = (lin & 7) * (NWG >> 3) + (lin >> 3);
  bx = wg & (GX - 1);
  int t = wg >> ctz_c(GX);
  by = t & (GY - 1);
  bz = t >> ctz_c(GY);
}

enum { EPI_OUT = 4, EPI_EXP = 2, EPI_PV = 5, EPI_QK8 = 6, EPI_V8 = 7 };

// TN GEMM (bf16): C[M,N] = A[M,K] * B[N,K]^T, TMx128 tile, BK=64, NT thr,
// 16x16x32 MFMA, sigma-staged B + packed epilogue stores. (OUT only now.)
template <int EPI, int TM, int NT, bool SWZ, int K, int LDA, int LDB,
          int LDC, int GX = 1, int GY = 1, int GZ = 1>
__global__ __launch_bounds__(NT) void gemm_tn(
    const bf16_t* __restrict__ A, const bf16_t* __restrict__ B, long sAb,
    long sBb, long sCb, void* __restrict__ Cv,
    const float* __restrict__ bias, const float* __restrict__ xres) {
  constexpr int NW = NT / 64;
  constexpr int WROWS = TM / (NW / 2);
  constexpr int MI = WROWS / 16;
  constexpr int RB = NT / 8;    // rows staged per batch
  constexpr int AB = TM / RB;   // A stage batches
  constexpr int BB = 128 / RB;  // B stage batches
  constexpr int PMAX = AB > BB ? AB : BB;
  __shared__ bf16_t Asm[TM * 64];
  __shared__ bf16_t Bsm[128 * 64];

  const int tid = threadIdx.x;
  const int w = tid >> 6, l = tid & 63;
  int bx = blockIdx.x, by = blockIdx.y, bz = blockIdx.z;
  if constexpr (SWZ) xcd_remap<GX, GY, GZ>(bx, by, bz);
  const int m0 = by * TM, n0 = bx * 128;

  const bf16_t* Ab = A + (long)bz * sAb + (long)m0 * LDA;
  const bf16_t* Bb = B + (long)bz * sBb + (long)n0 * LDB;

  const int r0 = 8 * w + (l >> 3);
  const int schunk = (l & 7) ^ (l >> 3);
  const bf16_t* ga = Ab + (long)r0 * LDA + schunk * 8;
  const bf16_t* gb = Bb + schunk * 8;
  bf16_t* lA = Asm + (8 * w) * 64;
  bf16_t* lB = Bsm + (8 * w) * 64;

  const int wr = w >> 1, wc = w & 1;
  const int fr = l & 15, fq = l >> 4, l7 = l & 7;

  floatx4 acc[MI][4];
  floatx4 zz = {0.f, 0.f, 0.f, 0.f};
#pragma unroll
  for (int i = 0; i < MI; i++)
#pragma unroll
    for (int j = 0; j < 4; j++) acc[i][j] = zz;

#pragma unroll 8
  for (int it = 0; it < K / 64; it++) {
    const int kb = it * 64;
#pragma unroll
    for (int p = 0; p < PMAX; p++) {
      if (p < AB) ld_g2l(ga + (long)(p * RB) * LDA + kb, lA + p * RB * 64);
      if (p < BB) {
        const int sig = sigma_row(r0 + RB * p);  // B rows sigma-permuted
        ld_g2l(gb + (long)sig * LDB + kb, lB + p * RB * 64);
      }
    }
    __syncthreads();
#pragma unroll
    for (int ks = 0; ks < 2; ks++) {
      bf16x8 af[MI], bfv[4];
      const int ch = (ks * 4 + fq);
#pragma unroll
      for (int mi = 0; mi < MI; mi++) {
        int row = wr * WROWS + mi * 16 + fr;
        af[mi] = *(const bf16x8*)(Asm + row * 64 + ((ch ^ l7) * 8));
      }
#pragma unroll
      for (int ni = 0; ni < 4; ni++) {
        int row = wc * 64 + ni * 16 + fr;  // row&7 == l7
        bfv[ni] = *(const bf16x8*)(Bsm + row * 64 + ((ch ^ l7) * 8));
      }
#pragma unroll
      for (int mi = 0; mi < MI; mi++)
#pragma unroll
        for (int ni = 0; ni < 4; ni++)
          acc[mi][ni] = __builtin_amdgcn_mfma_f32_16x16x32_bf16(
              af[mi], bfv[ni], acc[mi][ni], 0, 0, 0);
    }
    __syncthreads();
  }

  // epilogue: sigma staging => MFMA ni, lane fr holds global col 4fr+ni
  const int rb = fq * 4;
  const int gcolb = n0 + wc * 64 + 4 * fr;
#pragma unroll
  for (int mi = 0; mi < MI; mi++) {
#pragma unroll
    for (int i = 0; i < 4; i++) {
      const int grow = m0 + wr * WROWS + mi * 16 + rb + i;
      float v0 = acc[mi][0][i], v1 = acc[mi][1][i];
      float v2 = acc[mi][2][i], v3 = acc[mi][3][i];
      // EPI_OUT: grow = out channel, gcolb = b*P+p (4-aligned)
      int ob = gcolb >> 12, op = gcolb & 4095;
      long o = ((long)ob * CDIM + grow) * PDIM + op;
      const float4 xr = *(const float4*)(xres + o);
      const float bb = bias[grow];
      float4 ov = {v0 + bb + xr.x, v1 + bb + xr.y, v2 + bb + xr.z,
                   v3 + bb + xr.w};
      *(float4*)((float*)Cv + o) = ov;
    }
  }
}

// fp8 TN GEMM via MX-scaled MFMA:
//   C[M,N] op( (A[M,K]*2^(SA-127)) * (B[N,K]*2^(SB-127))^T )
// TMx128 tile, BK=128, NT thr, mfma_scale_f32_16x16x128_f8f6f4.
// EPI_EXP: C = fp8(exp2(acc)).  EPI_PV: C = bf16(acc/(P@1)) via ones-MFMA.
// EPI_QK8: C = fp8(acc + bias[col]) (fused q|k projection).
// EPI_V8 : C = fp8(acc + bias[row]) (v projection, channel-major out).
// DBUF=false: single-buffer 2-barrier loop (TLP regime, short K).
// DBUF=true : 2-phase __syncthreads ping-pong.
template <int EPI, int TM, int SA, int SB, int NT, int K, int LDA, int LDB,
          int LDC, int GX, int GY, int GZ, bool DBUF>
__global__ __launch_bounds__(NT) void gemm_f8(
    const uint8_t* __restrict__ A, const uint8_t* __restrict__ B, long sAb,
    long sBb, long sCb, void* __restrict__ Cv,
    const float* __restrict__ bias) {
  constexpr int NW = NT / 64;
  constexpr int WROWS = TM / (NW / 2);
  constexpr int MI = WROWS / 16;
  constexpr int RB = NT / 8;
  constexpr int AB = TM / RB;
  constexpr int BB = 128 / RB;
  constexpr int PMAX = AB > BB ? AB : BB;
  constexpr int NITER = K / 128;
  constexpr int NBUF = DBUF ? 2 : 1;
  static_assert(!DBUF || (NITER & 1) == 0, "ping-pong needs even iters");
  __shared__ uint8_t Asm[NBUF][TM * 128];
  __shared__ uint8_t Bsm[NBUF][128 * 128];

  const int tid = threadIdx.x;
  const int w = tid >> 6, l = tid & 63;
  int bx = blockIdx.x, by = blockIdx.y, bz = blockIdx.z;
  xcd_remap<GX, GY, GZ>(bx, by, bz);
  const int m0 = by * TM, n0 = bx * 128;

  const uint8_t* Ab = A + (long)bz * sAb + (long)m0 * LDA;
  const uint8_t* Bb = B + (long)bz * sBb + (long)n0 * LDB;

  const int r0 = 8 * w + (l >> 3);
  const int schunk = (l & 7) ^ (l >> 3);
  const uint8_t* ga = Ab + (long)r0 * LDA + schunk * 16;
  const uint8_t* gb = Bb + schunk * 16;
  const int lofs = (8 * w) * 128;

  const int wr = w >> 1, wc = w & 1;
  const int fr = l & 15, fq = l >> 4, l7 = l & 7;

  floatx4 acc[MI][4];
  floatx4 accr[MI];  // PV row sums (P @ ones)
#pragma unroll
  for (int i = 0; i < MI; i++) {
#pragma unroll
    for (int j = 0; j < 4; j++) acc[i][j] = floatx4{0.f, 0.f, 0.f, 0.f};
    accr[i] = floatx4{0.f, 0.f, 0.f, 0.f};
  }

  const int s0 = ((2 * fq) ^ l7) * 16;
  const int s1 = ((2 * fq + 1) ^ l7) * 16;

  // issue the global_load_lds for K-tile kb into buffer buf
  auto stage = [&](int buf, int kb) {
#pragma unroll
    for (int p = 0; p < PMAX; p++) {
      if (p < AB)
        ld_g2l(ga + (long)(p * RB) * LDA + kb, &Asm[buf][lofs + p * RB * 128]);
      if (p < BB) {
        const int sig = sigma_row(r0 + RB * p);  // B rows sigma-permuted
        ld_g2l(gb + (long)sig * LDB + kb, &Bsm[buf][lofs + p * RB * 128]);
      }
    }
  };
  // ds_read fragments from buffer buf and run the MFMA cluster
  auto compute = [&](int buf) {
    intx8 af[MI];
#pragma unroll
    for (int mi = 0; mi < MI; mi++)
      af[mi] =
          ld_frag(&Asm[buf][(wr * WROWS + mi * 16 + fr) * 128], s0, s1);
#pragma unroll
    for (int ni = 0; ni < 4; ni++) {
      // row&7 == l7 -> conflict-free
      intx8 bf = ld_frag(&Bsm[buf][(wc * 64 + ni * 16 + fr) * 128], s0, s1);
#pragma unroll
      for (int mi = 0; mi < MI; mi++)
        acc[mi][ni] = __builtin_amdgcn_mfma_scale_f32_16x16x128_f8f6f4(
            af[mi], bf, acc[mi][ni], 0, 0, 0, SA, 0, SB);
    }
    if constexpr (EPI == EPI_PV) {
      const int one8 = 0x38383838;  // 4x fp8 e4m3 1.0
      const intx8 ones = {one8, one8, one8, one8, one8, one8, one8, one8};
#pragma unroll
      for (int mi = 0; mi < MI; mi++)
        accr[mi] = __builtin_amdgcn_mfma_scale_f32_16x16x128_f8f6f4(
            af[mi], ones, accr[mi], 0, 0, 0, SA, 0, SB);
    }
  };

  if constexpr (DBUF) {
    stage(0, 0);
    __syncthreads();  // vmcnt(0) drain of prologue stage
#pragma unroll 1
    for (int it = 0; it < NITER; it += 2) {
      stage(1, (it + 1) * 128);  // issue next tile, compute under it
      compute(0);
      __syncthreads();
      if (it + 2 < NITER) stage(0, (it + 2) * 128);
      compute(1);
      __syncthreads();
    }
  } else {
#pragma unroll 1
    for (int it = 0; it < NITER; it++) {
      stage(0, it * 128);
      __syncthreads();
      compute(0);
      __syncthreads();
    }
  }

  const int rb = fq * 4;
  const int gcolb = n0 + wc * 64 + 4 * fr;
#pragma unroll
  for (int mi = 0; mi < MI; mi++) {
#pragma unroll
    for (int i = 0; i < 4; i++) {
      const int grow = m0 + wr * WROWS + mi * 16 + rb + i;
      if constexpr (EPI == EPI_EXP) {
        // acc already in log2 units (weight prescale + 2^-4 MX scale)
        float p0 = exp2f(acc[mi][0][i]), p1 = exp2f(acc[mi][1][i]);
        float p2 = exp2f(acc[mi][2][i]), p3 = exp2f(acc[mi][3][i]);
        *(uint32_t*)((uint8_t*)Cv + (long)bz * sCb + (long)grow * LDC +
                     gcolb) = pk_fp8x4(p0, p1, p2, p3);
      } else if constexpr (EPI == EPI_QK8) {
        const float4 b4 = *(const float4*)(bias + gcolb);
        *(uint32_t*)((uint8_t*)Cv + (long)grow * LDC + gcolb) =
            pk_fp8x4(acc[mi][0][i] + b4.x, acc[mi][1][i] + b4.y,
                     acc[mi][2][i] + b4.z, acc[mi][3][i] + b4.w);
      } else if constexpr (EPI == EPI_V8) {
        const float bb = bias[grow];
        *(uint32_t*)((uint8_t*)Cv + (long)grow * LDC + gcolb) =
            pk_fp8x4(acc[mi][0][i] + bb, acc[mi][1][i] + bb,
                     acc[mi][2][i] + bb, acc[mi][3][i] + bb);
      } else {  // EPI_PV: every column of accr == rowsum for this row
        const float inv = __builtin_amdgcn_rcpf(accr[mi][i]);
        bf16x4 o = {(bf16_t)(acc[mi][0][i] * inv),
                    (bf16_t)(acc[mi][1][i] * inv),
                    (bf16_t)(acc[mi][2][i] * inv),
                    (bf16_t)(acc[mi][3][i] * inv)};
        *(bf16x4*)((bf16_t*)Cv + (long)bz * sCb + (long)grow * LDC + gcolb) =
            o;
      }
    }
  }
}

// Stage 1: partial sums. Block i reads x[i*8192 .. +8192), writes (sum, sumsq).
__global__ __launch_bounds__(256) void gn_stats(const float* __restrict__ x,
                                                float2* __restrict__ part) {
  const int i = blockIdx.x;
  const float4* xp = (const float4*)(x + (long)i * 8192);
  float s0 = 0.f, s1 = 0.f;
  for (int j = threadIdx.x; j < 2048; j += 256) {
    float4 v = xp[j];
    s0 += v.x + v.y + v.z + v.w;
    s1 += v.x * v.x + v.y * v.y + v.z * v.z + v.w * v.w;
  }
  for (int o = 32; o; o >>= 1) {
    s0 += __shfl_xor(s0, o);
    s1 += __shfl_xor(s1, o);
  }
  __shared__ float r0[4], r1[4];
  if ((threadIdx.x & 63) == 0) {
    r0[threadIdx.x >> 6] = s0;
    r1[threadIdx.x >> 6] = s1;
  }
  __syncthreads();
  if (threadIdx.x == 0)
    part[i] = make_float2(r0[0] + r0[1] + r0[2] + r0[3],
                          r1[0] + r1[1] + r1[2] + r1[3]);
}

// Stage 2: normalize + transpose via LDS tile -> h8 fp8. Block = (b, 32 p).
__global__ __launch_bounds__(256) void gn_norm(
    const float* __restrict__ x, const float* __restrict__ gamma,
    const float* __restrict__ beta, const float2* __restrict__ part,
    uint8_t* __restrict__ h8) {
  const int b = blockIdx.x >> 7;
  const int p0 = (blockIdx.x & 127) * 32;
  const int t = threadIdx.x;
  __shared__ float gmS[512], btS[512];
  __shared__ float gmean[32], grstd[32];
  __shared__ __align__(16) bf16_t tile[32 * 520];

  if (t < 32) {
    const float2* pp = part + (b * 32 + t) * 8;
    float s0 = 0.f, s1 = 0.f;
#pragma unroll
    for (int s = 0; s < 8; s++) {
      float2 v = pp[s];
      s0 += v.x;
      s1 += v.y;
    }
    float mean = s0 * (1.f / 65536.f);
    float var = s1 * (1.f / 65536.f) - mean * mean;
    gmean[t] = mean;
    grstd[t] = rsqrtf(var + 1e-6f);
  }
  __syncthreads();
  for (int c = t; c < 512; c += 256) {
    float g = gamma[c] * grstd[c >> 4];
    gmS[c] = g;
    btS[c] = beta[c] - gmean[c >> 4] * g;
  }
  __syncthreads();

  const int cc = t >> 3, pcol = (t & 7) * 4;
  for (int pass = 0; pass < 16; pass++) {
    int c = pass * 32 + cc;
    float4 v = *(const float4*)(x + ((long)(b * 512 + c)) * 4096 + p0 + pcol);
    float g = gmS[c], bb = btS[c];
    tile[(pcol + 0) * 520 + c] = (bf16_t)(v.x * g + bb);
    tile[(pcol + 1) * 520 + c] = (bf16_t)(v.y * g + bb);
    tile[(pcol + 2) * 520 + c] = (bf16_t)(v.z * g + bb);
    tile[(pcol + 3) * 520 + c] = (bf16_t)(v.w * g + bb);
  }
  __syncthreads();
  const int p = t >> 3;
  uint8_t* orow = h8 + ((long)(b * 4096 + p0 + p)) * 512;
  const bf16_t* trow = tile + p * 520;
#pragma unroll
  for (int j = 0; j < 8; j++) {
    int ch = (t & 7) + 8 * j;
    bf16x8 hv = *(const bf16x8*)(trow + ch * 8);
    uint32_t lo = pk_fp8x4((float)hv[0], (float)hv[1], (float)hv[2],
                           (float)hv[3]);
    uint32_t hi = pk_fp8x4((float)hv[4], (float)hv[5], (float)hv[6],
                           (float)hv[7]);
    *(uint2*)(orow + ch * 8) = make_uint2(lo, hi);
  }
}

// Weights: wq,wk,wv -> fp8 e4m3 prescaled x2^6 (compensated by e8m0 scale
// 121 in the projection GEMMs); wq additionally x1.02014 = (log2e/sqrt(C))
// / 2^-4 so EXP's A-scale 123 yields log2-domain scores. wo -> bf16.
__global__ __launch_bounds__(256) void cvt_weights(
    const float* __restrict__ wq, const float* __restrict__ wk,
    const float* __restrict__ wv, const float* __restrict__ wo,
    const float* __restrict__ bq, const float* __restrict__ bk,
    uint8_t* __restrict__ w8qk, uint8_t* __restrict__ w8v,
    bf16_t* __restrict__ wo_b, float* __restrict__ bqk) {
  constexpr float QW = 1.02013936f * 64.f;
  constexpr float KW = 64.f;
  const int i4 = (blockIdx.x * 256 + threadIdx.x) * 4;
  float4 q = *(const float4*)(wq + i4);
  float4 k = *(const float4*)(wk + i4);
  float4 v = *(const float4*)(wv + i4);
  float4 o = *(const float4*)(wo + i4);
  *(uint32_t*)(w8qk + i4) =
      pk_fp8x4(q.x * QW, q.y * QW, q.z * QW, q.w * QW);
  *(uint32_t*)(w8qk + 262144 + i4) =
      pk_fp8x4(k.x * KW, k.y * KW, k.z * KW, k.w * KW);
  *(uint32_t*)(w8v + i4) = pk_fp8x4(v.x * KW, v.y * KW, v.z * KW, v.w * KW);
  bf16x4 ob = {(bf16_t)o.x, (bf16_t)o.y, (bf16_t)o.z, (bf16_t)o.w};
  *(bf16x4*)(wo_b + i4) = ob;
  if (i4 < 512) {
    constexpr float BQ = 1.02013936f;
    float4 bqv = *(const float4*)(bq + i4);
    float4 sb = {bqv.x * BQ, bqv.y * BQ, bqv.z * BQ, bqv.w * BQ};
    *(float4*)(bqk + i4) = sb;
  } else if (i4 < 1024) {
    *(float4*)(bqk + i4) = *(const float4*)(bk + i4 - 512);
  }
}

extern "C" void kernel_launch(void* const* d_in, const int* in_sizes, int n_in,
                              void* d_out, int out_size, void* d_ws,
                              size_t ws_size, hipStream_t stream) {
  const float* x = (const float*)d_in[0];
  const float* gamma = (const float*)d_in[1];
  const float* beta = (const float*)d_in[2];
  const float* wq = (const float*)d_in[3];
  const float* bq = (const float*)d_in[4];
  const float* wk = (const float*)d_in[5];
  const float* bk = (const float*)d_in[6];
  const float* wv = (const float*)d_in[7];
  const float* bv = (const float*)d_in[8];
  const float* wo = (const float*)d_in[9];
  const float* bo = (const float*)d_in[10];

  char* ws = (char*)d_ws;
  uint8_t* h8 = (uint8_t*)(ws);                 // [16384,512] fp8  @0 (8MB)
  uint8_t* qk8 = (uint8_t*)(ws + (16l << 20));  // [16384,1024] fp8 @16MB
  uint8_t* v_c = (uint8_t*)(ws + (48l << 20));  // [512,16384] fp8  @48MB
  bf16_t* h_at = (bf16_t*)(ws + (64l << 20));   // [16384,512] bf16 @64MB
  bf16_t* w_b = (bf16_t*)(ws + (80l << 20));    // wo bf16 [512,512] @80MB
  uint8_t* w8qk = (uint8_t*)(ws + (81l << 20)); // [1024,512] fp8   @81MB
  uint8_t* w8v = (uint8_t*)(ws + (82l << 20));  // [512,512] fp8    @82MB
  float2* part = (float2*)(ws + (83l << 20));   // [1024] partials  @83MB
  float* bqk = (float*)(ws + (83l << 20) + (64l << 10));  // [1024]
  uint8_t* Sbuf = (uint8_t*)(ws + (84l << 20)); // [4,4096,4096] fp8 @84MB

  const long sQK8 = (long)PDIM * 1024;  // bytes per batch of qk8
  const long sS = (long)PDIM * PDIM;    // 16777216

  cvt_weights<<<256, 256, 0, stream>>>(wq, wk, wv, wo, bq, bk, w8qk, w8v,
                                       w_b, bqk);
  gn_stats<<<1024, 256, 0, stream>>>(x, part);
  gn_norm<<<512, 256, 0, stream>>>(x, gamma, beta, part, h8);
  // fused q|k projection -> fp8: qk8 = h8 @ [wq;wk]^T (SB=121 undoes x64)
  gemm_f8<EPI_QK8, 128, 127, 121, 256, 512, 512, 512, 1024, 8, 128, 1, false>
      <<<dim3(8, 128, 1), 256, 0, stream>>>(h8, w8qk, 0, 0, 0, qk8, bqk);
  // v projection -> fp8 channel-major: v_c = wv @ h8^T (SA=121 undoes x64)
  gemm_f8<EPI_V8, 128, 121, 127, 256, 512, 512, 512, 16384, 128, 4, 1, false>
      <<<dim3(128, 4, 1), 256, 0, stream>>>(w8v, h8, 0, 0, 0, v_c, bv);
  // P = exp2(2^-4 * q8 k8^T) fp8 (unnormalized; sums computed in PV)
  gemm_f8<EPI_EXP, 128, 123, 127, 256, 512, 1024, 1024, 4096, 32, 32, 4,
          false><<<dim3(32, 32, 4), 256, 0, stream>>>(
      qk8, qk8 + 512, sQK8, sQK8, sS, Sbuf, nullptr);
  // h_at = (P @ v^T) / (P @ 1) — 256x128 tile, 512 thr, dbuf
  gemm_f8<EPI_PV, 256, 127, 127, 512, 4096, 4096, 16384, 512, 4, 16, 4, true>
      <<<dim3(4, 16, 4), 512, 0, stream>>>(Sbuf, v_c, sS, 4096,
                                           (long)PDIM * CDIM, h_at, nullptr);
  gemm_tn<EPI_OUT, 64, 256, false, 512, 512, 512, 4096>
      <<<dim3(128, 8, 1), 256, 0, stream>>>(w_b, h_at, 0, 0, 0, d_out, bo, x);
}